// Round 1
// baseline (1445.076 us; speedup 1.0000x reference)
//
#include <hip/hip_runtime.h>
#include <math.h>

#define B_    256
#define S_    128
#define ENCD  1024
#define DECU  512
#define UNITS 1024
#define VOCAB 32000
#define EMB_  300
#define INDIM 1324   // ENCD + EMB
#define G3    3072   // 3*UNITS

// ---------------- K1: q = state @ W2 + b2   (256 x 512, K=1024) ----------------
__global__ __launch_bounds__(256) void k_q(const float* __restrict__ state,
                                           const float* __restrict__ W2,
                                           const float* __restrict__ b2,
                                           float* __restrict__ q) {
  int b = blockIdx.x;
  __shared__ float s[UNITS];
  for (int k = threadIdx.x; k < UNITS; k += 256) s[k] = state[b * UNITS + k];
  __syncthreads();
  int j0 = threadIdx.x;  // 2 cols per thread
  float a0 = b2[j0], a1 = b2[j0 + 256];
  for (int k = 0; k < UNITS; ++k) {
    float sv = s[k];
    a0 += sv * W2[k * DECU + j0];
    a1 += sv * W2[k * DECU + j0 + 256];
  }
  q[b * DECU + j0] = a0;
  q[b * DECU + j0 + 256] = a1;
}

// ---------------- K2: score_part = per-jtile sum_j V[j]*tanh(enc@W1 + b1 + q) ----
// C-tile 64(rows of flattened b*s) x 64(j), K=1024, 256 threads, 4x4 microtile.
__global__ __launch_bounds__(256) void k_score(const float* __restrict__ enc,
                                               const float* __restrict__ W1,
                                               const float* __restrict__ b1,
                                               const float* __restrict__ q,
                                               const float* __restrict__ V,
                                               float* __restrict__ score_part) {
  __shared__ float As[32][68];
  __shared__ float Bs[32][64];
  __shared__ float red[16][65];
  int m0 = blockIdx.x * 64, n0 = blockIdx.y * 64;
  int t = threadIdx.x, tr = t >> 4, tc = t & 15;
  float acc[4][4] = {};
  for (int k0 = 0; k0 < ENCD; k0 += 32) {
#pragma unroll
    for (int i = 0; i < 8; ++i) {
      int e = i * 256 + t, m = e >> 5, kk = e & 31;
      As[kk][m] = enc[(size_t)(m0 + m) * ENCD + k0 + kk];
    }
#pragma unroll
    for (int i = 0; i < 8; ++i) {
      int e = i * 256 + t, kk = e >> 6, n = e & 63;
      Bs[kk][n] = W1[(size_t)(k0 + kk) * DECU + n0 + n];
    }
    __syncthreads();
#pragma unroll
    for (int kk = 0; kk < 32; ++kk) {
      float a[4], bb[4];
#pragma unroll
      for (int i = 0; i < 4; ++i) a[i] = As[kk][tr * 4 + i];
#pragma unroll
      for (int j = 0; j < 4; ++j) bb[j] = Bs[kk][tc * 4 + j];
#pragma unroll
      for (int i = 0; i < 4; ++i)
#pragma unroll
        for (int j = 0; j < 4; ++j) acc[i][j] += a[i] * bb[j];
    }
    __syncthreads();
  }
  // epilogue: tanh + dot with V over this block's 64 j's
  float rsum[4] = {0.f, 0.f, 0.f, 0.f};
  int bb_ = (m0) >> 7;  // 64-row tile lies within one batch row (128 rows per b)
#pragma unroll
  for (int j = 0; j < 4; ++j) {
    int jg = n0 + tc * 4 + j;
    float vj = V[jg];
    float b1j = b1[jg];
    float qv = q[bb_ * DECU + jg];
#pragma unroll
    for (int i = 0; i < 4; ++i) {
      float tv = tanhf(acc[i][j] + b1j + qv);
      rsum[i] += vj * tv;
    }
  }
#pragma unroll
  for (int i = 0; i < 4; ++i) red[tc][tr * 4 + i] = rsum[i];
  __syncthreads();
  if (t < 64) {
    float s = 0.f;
#pragma unroll
    for (int c = 0; c < 16; ++c) s += red[c][t];
    score_part[(size_t)(m0 + t) * 8 + blockIdx.y] = s;
  }
}

// ---------------- K3: softmax over S + context + xi assembly ----------------
__global__ __launch_bounds__(256) void k_attn_ctx(const float* __restrict__ score_part,
                                                  const float* __restrict__ bV,
                                                  const float* __restrict__ enc,
                                                  const int* __restrict__ x,
                                                  const float* __restrict__ emb,
                                                  float* __restrict__ attn_out,
                                                  float* __restrict__ xi) {
  int b = blockIdx.x, t = threadIdx.x;
  __shared__ float a_s[S_];
  if (t < S_) {
    float s = bV[0];
#pragma unroll
    for (int jt = 0; jt < 8; ++jt) s += score_part[(size_t)(b * S_ + t) * 8 + jt];
    a_s[t] = s;
  }
  __syncthreads();
  float mx = -INFINITY;
  for (int s = 0; s < S_; ++s) mx = fmaxf(mx, a_s[s]);
  float sum = 0.f;
  for (int s = 0; s < S_; ++s) sum += expf(a_s[s] - mx);
  float inv = 1.f / sum;
  __syncthreads();
  if (t < S_) {
    float av = expf(a_s[t] - mx) * inv;
    a_s[t] = av;
    attn_out[b * S_ + t] = av;
  }
  __syncthreads();
  // context -> xi[b, 0:1024]
  for (int k = t; k < ENCD; k += 256) {
    float acc = 0.f;
#pragma unroll 4
    for (int s = 0; s < S_; ++s) acc += a_s[s] * enc[((size_t)b * S_ + s) * ENCD + k];
    xi[(size_t)b * INDIM + k] = acc;
  }
  // embedding -> xi[b, 1024:1324]
  int xb = x[b];
  for (int e = t; e < EMB_; e += 256) xi[(size_t)b * INDIM + ENCD + e] = emb[(size_t)xb * EMB_ + e];
}

// ---------------- generic 64x64 fp32 GEMM with bias: C = A@B + bias ----------------
__global__ __launch_bounds__(256) void k_gemm64(const float* __restrict__ A,
                                                const float* __restrict__ Bm,
                                                const float* __restrict__ bias,
                                                float* __restrict__ C,
                                                int K, int N) {
  __shared__ float As[32][68];
  __shared__ float Bs[32][64];
  int m0 = blockIdx.x * 64, n0 = blockIdx.y * 64;
  int t = threadIdx.x, tr = t >> 4, tc = t & 15;
  float acc[4][4] = {};
  for (int k0 = 0; k0 < K; k0 += 32) {
#pragma unroll
    for (int i = 0; i < 8; ++i) {
      int e = i * 256 + t, m = e >> 5, kk = e & 31;
      int k = k0 + kk;
      As[kk][m] = (k < K) ? A[(size_t)(m0 + m) * K + k] : 0.f;
    }
#pragma unroll
    for (int i = 0; i < 8; ++i) {
      int e = i * 256 + t, kk = e >> 6, n = e & 63;
      int k = k0 + kk;
      Bs[kk][n] = (k < K) ? Bm[(size_t)k * N + n0 + n] : 0.f;
    }
    __syncthreads();
#pragma unroll
    for (int kk = 0; kk < 32; ++kk) {
      float a[4], bb[4];
#pragma unroll
      for (int i = 0; i < 4; ++i) a[i] = As[kk][tr * 4 + i];
#pragma unroll
      for (int j = 0; j < 4; ++j) bb[j] = Bs[kk][tc * 4 + j];
#pragma unroll
      for (int i = 0; i < 4; ++i)
#pragma unroll
        for (int j = 0; j < 4; ++j) acc[i][j] += a[i] * bb[j];
    }
    __syncthreads();
  }
#pragma unroll
  for (int i = 0; i < 4; ++i) {
    int m = m0 + tr * 4 + i;
    int n = n0 + tc * 4;
    float4 o = make_float4(acc[i][0] + bias[n], acc[i][1] + bias[n + 1],
                           acc[i][2] + bias[n + 2], acc[i][3] + bias[n + 3]);
    *(float4*)&C[(size_t)m * N + n] = o;
  }
}

// ---------------- K6: GRU gates ----------------
__global__ __launch_bounds__(256) void k_gates(const float* __restrict__ mx,
                                               const float* __restrict__ mh,
                                               const float* __restrict__ state,
                                               float* __restrict__ h_out) {
  int idx = blockIdx.x * 256 + threadIdx.x;  // < 256*1024
  int b = idx >> 10, j = idx & 1023;
  const float* mxr = mx + (size_t)b * G3;
  const float* mhr = mh + (size_t)b * G3;
  float z = 1.f / (1.f + expf(-(mxr[j] + mhr[j])));
  float r = 1.f / (1.f + expf(-(mxr[UNITS + j] + mhr[UNITS + j])));
  float hh = tanhf(mxr[2 * UNITS + j] + r * mhr[2 * UNITS + j]);
  float st = state[idx];
  h_out[idx] = z * st + (1.f - z) * hh;
}

// ---------------- K8: in-place row softmax over VOCAB ----------------
__global__ __launch_bounds__(1024) void k_softmax(float* __restrict__ logits, int N) {
  int b = blockIdx.x;
  float* row = logits + (size_t)b * N;
  __shared__ float smax[16];
  __shared__ float ssum[16];
  int lane = threadIdx.x & 63, w = threadIdx.x >> 6;
  float m = -INFINITY;
  for (int i = threadIdx.x; i < N; i += 1024) m = fmaxf(m, row[i]);
  for (int o = 32; o >= 1; o >>= 1) m = fmaxf(m, __shfl_xor(m, o));
  if (lane == 0) smax[w] = m;
  __syncthreads();
  float m2 = -INFINITY;
#pragma unroll
  for (int i = 0; i < 16; ++i) m2 = fmaxf(m2, smax[i]);
  float s = 0.f;
  for (int i = threadIdx.x; i < N; i += 1024) s += expf(row[i] - m2);
  for (int o = 32; o >= 1; o >>= 1) s += __shfl_xor(s, o);
  if (lane == 0) ssum[w] = s;
  __syncthreads();
  float s2 = 0.f;
#pragma unroll
  for (int i = 0; i < 16; ++i) s2 += ssum[i];
  float inv = 1.f / s2;
  for (int i = threadIdx.x; i < N; i += 1024) row[i] = expf(row[i] - m2) * inv;
}

extern "C" void kernel_launch(void* const* d_in, const int* in_sizes, int n_in,
                              void* d_out, int out_size, void* d_ws, size_t ws_size,
                              hipStream_t stream) {
  const int*   x     = (const int*)d_in[0];
  const float* state = (const float*)d_in[1];
  const float* enc   = (const float*)d_in[2];
  const float* emb   = (const float*)d_in[3];
  const float* W1    = (const float*)d_in[4];
  const float* b1    = (const float*)d_in[5];
  const float* W2    = (const float*)d_in[6];
  const float* b2    = (const float*)d_in[7];
  const float* V     = (const float*)d_in[8];
  const float* bV    = (const float*)d_in[9];
  const float* gru_k = (const float*)d_in[10];
  const float* gru_rk= (const float*)d_in[11];
  const float* gru_b = (const float*)d_in[12];
  const float* fc_W  = (const float*)d_in[13];
  const float* fc_b  = (const float*)d_in[14];

  float* out   = (float*)d_out;
  float* probs = out;                               // 256*32000
  float* h_out = out + (size_t)B_ * VOCAB;          // 256*1024
  float* attn  = h_out + (size_t)B_ * UNITS;        // 256*128

  float* ws      = (float*)d_ws;
  float* q       = ws;                              // 131072
  float* sc_part = q + B_ * DECU;                   // 32768*8
  float* xi      = sc_part + (size_t)B_ * S_ * 8;   // 256*1324
  float* mx      = xi + (size_t)B_ * INDIM;         // 256*3072
  float* mh      = mx + (size_t)B_ * G3;            // 256*3072

  k_q<<<B_, 256, 0, stream>>>(state, W2, b2, q);
  k_score<<<dim3(B_ * S_ / 64, DECU / 64), 256, 0, stream>>>(enc, W1, b1, q, V, sc_part);
  k_attn_ctx<<<B_, 256, 0, stream>>>(sc_part, bV, enc, x, emb, attn, xi);
  k_gemm64<<<dim3(B_ / 64, G3 / 64), 256, 0, stream>>>(xi, gru_k, gru_b, mx, INDIM, G3);
  k_gemm64<<<dim3(B_ / 64, G3 / 64), 256, 0, stream>>>(state, gru_rk, gru_b + G3, mh, UNITS, G3);
  k_gates<<<(B_ * UNITS) / 256, 256, 0, stream>>>(mx, mh, state, h_out);
  k_gemm64<<<dim3(B_ / 64, VOCAB / 64), 256, 0, stream>>>(h_out, fc_W, fc_b, probs, UNITS, VOCAB);
  k_softmax<<<B_, 1024, 0, stream>>>(probs, VOCAB);
}

// Round 2
// 583.473 us; speedup vs baseline: 2.4767x; 2.4767x over previous
//
#include <hip/hip_runtime.h>
#include <math.h>

#define B_    256
#define S_    128
#define ENCD  1024
#define DECU  512
#define UNITS 1024
#define VOCAB 32000
#define EMB_  300
#define INDIM 1324   // ENCD + EMB
#define G3    3072   // 3*UNITS

typedef __bf16 bf16x8 __attribute__((ext_vector_type(8)));
typedef __bf16 bf16x4 __attribute__((ext_vector_type(4)));
typedef float  f32x4  __attribute__((ext_vector_type(4)));

#define MFMA16(a, b, c) __builtin_amdgcn_mfma_f32_16x16x32_bf16((a), (b), (c), 0, 0, 0)

// ============ generic MFMA GEMM, M=256 fixed, BN=64 per block ============
// C[256][N] = A[256][K] @ B[K][N] + bias[N]   (A,B fp32 in HBM, bf16 in LDS)
// 512 threads = 8 waves; wave w owns rows 32w..32w+31, all 64 cols.
__global__ __launch_bounds__(512) void k_gemm_m256(const float* __restrict__ A,
                                                   const float* __restrict__ B,
                                                   const float* __restrict__ bias,
                                                   float* __restrict__ C,
                                                   int K, int N) {
  __shared__ __align__(16) __bf16 As[256][40];    // row stride 80 B (16B mult)
  __shared__ __align__(16) __bf16 Bs_t[64][40];   // B transposed: [n][k]
  int tid = threadIdx.x;
  int lane = tid & 63, w = tid >> 6;
  int n0 = blockIdx.x * 64;
  int lrow = lane & 15, lk = (lane >> 4) * 8;
  int r0 = w * 32;
  f32x4 acc[2][4] = {};

  int nk = (K + 31) / 32;
  for (int it = 0; it < nk; ++it) {
    int k0 = it * 32;
    // ---- stage A: thread -> row m=tid>>1, 16 k at kb=(tid&1)*16
    {
      int m = tid >> 1, kb = (tid & 1) * 16;
      const float* arow = A + (size_t)m * K + k0 + kb;
      __bf16 tmp[16];
      if (k0 + 32 <= K) {
#pragma unroll
        for (int v = 0; v < 4; ++v) {
          float4 f = *(const float4*)(arow + v * 4);
          tmp[v * 4 + 0] = (__bf16)f.x;
          tmp[v * 4 + 1] = (__bf16)f.y;
          tmp[v * 4 + 2] = (__bf16)f.z;
          tmp[v * 4 + 3] = (__bf16)f.w;
        }
      } else {
#pragma unroll
        for (int e = 0; e < 16; ++e) {
          int k = k0 + kb + e;
          tmp[e] = (k < K) ? (__bf16)arow[e] : (__bf16)0.f;
        }
      }
      *(bf16x8*)&As[m][kb] = *(bf16x8*)&tmp[0];
      *(bf16x8*)&As[m][kb + 8] = *(bf16x8*)&tmp[8];
    }
    // ---- stage B (transposed): thread -> col n=tid&63, 4 k at kb2=(tid>>6)*4
    {
      int n = tid & 63, kb2 = (tid >> 6) * 4;
      __bf16 tb[4];
#pragma unroll
      for (int r = 0; r < 4; ++r) {
        int k = k0 + kb2 + r;
        tb[r] = (k < K) ? (__bf16)B[(size_t)k * N + n0 + n] : (__bf16)0.f;
      }
      *(bf16x4*)&Bs_t[n][kb2] = *(bf16x4*)&tb[0];
    }
    __syncthreads();
    // ---- MFMA
    bf16x8 a0 = *(bf16x8*)&As[r0 + lrow][lk];
    bf16x8 a1 = *(bf16x8*)&As[r0 + 16 + lrow][lk];
#pragma unroll
    for (int ni = 0; ni < 4; ++ni) {
      bf16x8 bb = *(bf16x8*)&Bs_t[ni * 16 + lrow][lk];
      acc[0][ni] = MFMA16(a0, bb, acc[0][ni]);
      acc[1][ni] = MFMA16(a1, bb, acc[1][ni]);
    }
    __syncthreads();
  }
  // ---- epilogue: bias + store fp32
#pragma unroll
  for (int mi = 0; mi < 2; ++mi)
#pragma unroll
    for (int ni = 0; ni < 4; ++ni) {
      int colg = n0 + ni * 16 + lrow;
      float bv = bias[colg];
#pragma unroll
      for (int reg = 0; reg < 4; ++reg) {
        int rowg = r0 + mi * 16 + (lane >> 4) * 4 + reg;
        C[(size_t)rowg * N + colg] = acc[mi][ni][reg] + bv;
      }
    }
}

// ============ score kernel: per-jtile V.tanh(enc@W1 + b1 + q) partials ============
// BM=128 (one batch row b = blockIdx.x), BN=128 (blockIdx.y of 4), K=1024.
// 8 waves: wr=w>>1 (4 row strips of 32), wn=w&1 (2 col strips of 64).
__global__ __launch_bounds__(512) void k_score_mfma(const float* __restrict__ enc,
                                                    const float* __restrict__ W1,
                                                    const float* __restrict__ b1,
                                                    const float* __restrict__ q,
                                                    const float* __restrict__ V,
                                                    float* __restrict__ score_part) {
  __shared__ __align__(16) __bf16 As[128][40];
  __shared__ __align__(16) __bf16 Bs_t[128][40];
  int tid = threadIdx.x;
  int lane = tid & 63, w = tid >> 6;
  int wr = w >> 1, wn = w & 1;
  int b = blockIdx.x;             // batch index; m0 = b*128
  int m0 = b * 128;
  int n0 = blockIdx.y * 128;
  int lrow = lane & 15, lk = (lane >> 4) * 8;
  int r0 = wr * 32, c0 = wn * 64;
  f32x4 acc[2][4] = {};

  for (int k0 = 0; k0 < ENCD; k0 += 32) {
    // stage A (enc rows): thread -> m=tid>>2 (0..127), 8 k at kb=(tid&3)*8
    {
      int m = tid >> 2, kb = (tid & 3) * 8;
      const float* arow = enc + (size_t)(m0 + m) * ENCD + k0 + kb;
      float4 f0 = *(const float4*)(arow);
      float4 f1 = *(const float4*)(arow + 4);
      __bf16 tmp[8] = {(__bf16)f0.x, (__bf16)f0.y, (__bf16)f0.z, (__bf16)f0.w,
                       (__bf16)f1.x, (__bf16)f1.y, (__bf16)f1.z, (__bf16)f1.w};
      *(bf16x8*)&As[m][kb] = *(bf16x8*)&tmp[0];
    }
    // stage B (W1, transposed): thread -> n=tid&127, 8 k at kb=(tid>>7)*8
    {
      int n = tid & 127, kb = (tid >> 7) * 8;
      __bf16 tb[8];
#pragma unroll
      for (int r = 0; r < 8; ++r)
        tb[r] = (__bf16)W1[(size_t)(k0 + kb + r) * DECU + n0 + n];
      *(bf16x8*)&Bs_t[n][kb] = *(bf16x8*)&tb[0];
    }
    __syncthreads();
    bf16x8 a0 = *(bf16x8*)&As[r0 + lrow][lk];
    bf16x8 a1 = *(bf16x8*)&As[r0 + 16 + lrow][lk];
#pragma unroll
    for (int ni = 0; ni < 4; ++ni) {
      bf16x8 bb = *(bf16x8*)&Bs_t[c0 + ni * 16 + lrow][lk];
      acc[0][ni] = MFMA16(a0, bb, acc[0][ni]);
      acc[1][ni] = MFMA16(a1, bb, acc[1][ni]);
    }
    __syncthreads();
  }
  // epilogue: tanh + dot V over this block's 128 j, reduce over 16-lane groups
  float psum[2][4] = {};
#pragma unroll
  for (int mi = 0; mi < 2; ++mi)
#pragma unroll
    for (int ni = 0; ni < 4; ++ni) {
      int j = n0 + c0 + ni * 16 + lrow;
      float vj = V[j], b1j = b1[j], qv = q[b * DECU + j];
#pragma unroll
      for (int reg = 0; reg < 4; ++reg)
        psum[mi][reg] += vj * tanhf(acc[mi][ni][reg] + b1j + qv);
    }
#pragma unroll
  for (int off = 1; off < 16; off <<= 1)
#pragma unroll
    for (int mi = 0; mi < 2; ++mi)
#pragma unroll
      for (int reg = 0; reg < 4; ++reg)
        psum[mi][reg] += __shfl_xor(psum[mi][reg], off);
  if (lrow == 0) {
#pragma unroll
    for (int mi = 0; mi < 2; ++mi)
#pragma unroll
      for (int reg = 0; reg < 4; ++reg) {
        int rowg = m0 + r0 + mi * 16 + (lane >> 4) * 4 + reg;
        score_part[(size_t)rowg * 8 + blockIdx.y * 2 + wn] = psum[mi][reg];
      }
  }
}

// ---------------- softmax over S + context + xi assembly ----------------
__global__ __launch_bounds__(256) void k_attn_ctx(const float* __restrict__ score_part,
                                                  const float* __restrict__ bV,
                                                  const float* __restrict__ enc,
                                                  const int* __restrict__ x,
                                                  const float* __restrict__ emb,
                                                  float* __restrict__ attn_out,
                                                  float* __restrict__ xi) {
  int b = blockIdx.x, t = threadIdx.x;
  __shared__ float a_s[S_];
  if (t < S_) {
    float s = bV[0];
#pragma unroll
    for (int jt = 0; jt < 8; ++jt) s += score_part[(size_t)(b * S_ + t) * 8 + jt];
    a_s[t] = s;
  }
  __syncthreads();
  float mx = -INFINITY;
  for (int s = 0; s < S_; ++s) mx = fmaxf(mx, a_s[s]);
  float sum = 0.f;
  for (int s = 0; s < S_; ++s) sum += expf(a_s[s] - mx);
  float inv = 1.f / sum;
  __syncthreads();
  if (t < S_) {
    float av = expf(a_s[t] - mx) * inv;
    a_s[t] = av;
    attn_out[b * S_ + t] = av;
  }
  __syncthreads();
  for (int k = t; k < ENCD; k += 256) {
    float acc = 0.f;
#pragma unroll 4
    for (int s = 0; s < S_; ++s) acc += a_s[s] * enc[((size_t)b * S_ + s) * ENCD + k];
    xi[(size_t)b * INDIM + k] = acc;
  }
  int xb = x[b];
  for (int e = t; e < EMB_; e += 256) xi[(size_t)b * INDIM + ENCD + e] = emb[(size_t)xb * EMB_ + e];
}

// ---------------- GRU gates ----------------
__global__ __launch_bounds__(256) void k_gates(const float* __restrict__ mx,
                                               const float* __restrict__ mh,
                                               const float* __restrict__ state,
                                               float* __restrict__ h_out) {
  int idx = blockIdx.x * 256 + threadIdx.x;
  int b = idx >> 10, j = idx & 1023;
  const float* mxr = mx + (size_t)b * G3;
  const float* mhr = mh + (size_t)b * G3;
  float z = 1.f / (1.f + expf(-(mxr[j] + mhr[j])));
  float r = 1.f / (1.f + expf(-(mxr[UNITS + j] + mhr[UNITS + j])));
  float hh = tanhf(mxr[2 * UNITS + j] + r * mhr[2 * UNITS + j]);
  float st = state[idx];
  h_out[idx] = z * st + (1.f - z) * hh;
}

// ---------------- in-place row softmax over VOCAB ----------------
__global__ __launch_bounds__(1024) void k_softmax(float* __restrict__ logits, int N) {
  int b = blockIdx.x;
  float* row = logits + (size_t)b * N;
  __shared__ float smax[16];
  __shared__ float ssum[16];
  int lane = threadIdx.x & 63, w = threadIdx.x >> 6;
  float m = -INFINITY;
  for (int i = threadIdx.x; i < N; i += 1024) m = fmaxf(m, row[i]);
  for (int o = 32; o >= 1; o >>= 1) m = fmaxf(m, __shfl_xor(m, o));
  if (lane == 0) smax[w] = m;
  __syncthreads();
  float m2 = -INFINITY;
#pragma unroll
  for (int i = 0; i < 16; ++i) m2 = fmaxf(m2, smax[i]);
  float s = 0.f;
  for (int i = threadIdx.x; i < N; i += 1024) s += expf(row[i] - m2);
  for (int o = 32; o >= 1; o >>= 1) s += __shfl_xor(s, o);
  if (lane == 0) ssum[w] = s;
  __syncthreads();
  float s2 = 0.f;
#pragma unroll
  for (int i = 0; i < 16; ++i) s2 += ssum[i];
  float inv = 1.f / s2;
  for (int i = threadIdx.x; i < N; i += 1024) row[i] = expf(row[i] - m2) * inv;
}

extern "C" void kernel_launch(void* const* d_in, const int* in_sizes, int n_in,
                              void* d_out, int out_size, void* d_ws, size_t ws_size,
                              hipStream_t stream) {
  const int*   x     = (const int*)d_in[0];
  const float* state = (const float*)d_in[1];
  const float* enc   = (const float*)d_in[2];
  const float* emb   = (const float*)d_in[3];
  const float* W1    = (const float*)d_in[4];
  const float* b1    = (const float*)d_in[5];
  const float* W2    = (const float*)d_in[6];
  const float* b2    = (const float*)d_in[7];
  const float* V     = (const float*)d_in[8];
  const float* bV    = (const float*)d_in[9];
  const float* gru_k = (const float*)d_in[10];
  const float* gru_rk= (const float*)d_in[11];
  const float* gru_b = (const float*)d_in[12];
  const float* fc_W  = (const float*)d_in[13];
  const float* fc_b  = (const float*)d_in[14];

  float* out   = (float*)d_out;
  float* probs = out;                               // 256*32000
  float* h_out = out + (size_t)B_ * VOCAB;          // 256*1024
  float* attn  = h_out + (size_t)B_ * UNITS;        // 256*128

  float* ws      = (float*)d_ws;
  float* q       = ws;                              // 131072
  float* sc_part = q + B_ * DECU;                   // 32768*8
  float* xi      = sc_part + (size_t)B_ * S_ * 8;   // 256*1324
  float* mx      = xi + (size_t)B_ * INDIM;         // 256*3072
  float* mh      = mx + (size_t)B_ * G3;            // 256*3072

  // q = state @ W2 + b2
  k_gemm_m256<<<DECU / 64, 512, 0, stream>>>(state, W2, b2, q, UNITS, DECU);
  // score partials
  k_score_mfma<<<dim3(B_, 4), 512, 0, stream>>>(enc, W1, b1, q, V, sc_part);
  // softmax + context + xi
  k_attn_ctx<<<B_, 256, 0, stream>>>(sc_part, bV, enc, x, emb, attn, xi);
  // GRU input/recurrent GEMMs
  k_gemm_m256<<<G3 / 64, 512, 0, stream>>>(xi, gru_k, gru_b, mx, INDIM, G3);
  k_gemm_m256<<<G3 / 64, 512, 0, stream>>>(state, gru_rk, gru_b + G3, mh, UNITS, G3);
  // gates
  k_gates<<<(B_ * UNITS) / 256, 256, 0, stream>>>(mx, mh, state, h_out);
  // FC logits
  k_gemm_m256<<<VOCAB / 64, 512, 0, stream>>>(h_out, fc_W, fc_b, probs, UNITS, VOCAB);
  // softmax
  k_softmax<<<B_, 1024, 0, stream>>>(probs, VOCAB);
}

// Round 3
// 363.499 us; speedup vs baseline: 3.9755x; 1.6052x over previous
//
#include <hip/hip_runtime.h>
#include <math.h>

#define B_    256
#define S_    128
#define ENCD  1024
#define DECU  512
#define UNITS 1024
#define VOCAB 32000
#define EMB_  300
#define INDIM 1324   // ENCD + EMB
#define KPADX 1344   // INDIM padded to 64
#define G3    3072   // 3*UNITS

typedef __bf16 bf16x8 __attribute__((ext_vector_type(8)));
typedef __bf16 bf16x4 __attribute__((ext_vector_type(4)));
typedef __bf16 bf16x2 __attribute__((ext_vector_type(2)));
typedef float  f32x4  __attribute__((ext_vector_type(4)));

#define MFMA16(a, b, c) __builtin_amdgcn_mfma_f32_16x16x32_bf16((a), (b), (c), 0, 0, 0)

// ---------------- convert state f32 -> bf16 ----------------
__global__ __launch_bounds__(256) void k_cvt_state(const float* __restrict__ in,
                                                   __bf16* __restrict__ out) {
  int i4 = blockIdx.x * 256 + threadIdx.x;   // 65536 float4s
  float4 f = *(const float4*)(in + (size_t)i4 * 4);
  bf16x4 o = {(__bf16)f.x, (__bf16)f.y, (__bf16)f.z, (__bf16)f.w};
  *(bf16x4*)(out + (size_t)i4 * 4) = o;
}

// ============ generic MFMA GEMM: C[256][N] = A_bf[256][ldaK] @ B_f32[K][N] + bias ===========
// BM in {64,256}, BN=128, BK=64, 512 threads (8 waves).
template <int BM>
__global__ __launch_bounds__(512) void k_gemm(const __bf16* __restrict__ A, int ldaK,
                                              const float* __restrict__ B,
                                              const float* __restrict__ bias,
                                              float* __restrict__ C, int K, int N) {
  constexpr int WR = (BM == 256) ? 4 : 2;      // wave rows
  constexpr int WN = 8 / WR;                   // wave cols
  constexpr int MI = BM / (WR * 16);           // frags per wave (m)
  constexpr int NI = 128 / (WN * 16);          // frags per wave (n)
  __shared__ __align__(16) __bf16 As[BM][72];
  __shared__ __align__(16) __bf16 Bs[128][72];
  int tid = threadIdx.x, lane = tid & 63, w = tid >> 6;
  int wr = (BM == 256) ? (w >> 1) : (w >> 2);
  int wn = (BM == 256) ? (w & 1) : (w & 3);
  int m0 = blockIdx.x * BM, n0 = blockIdx.y * 128;
  int lrow = lane & 15, lk = (lane >> 4) * 8;
  int r0 = wr * MI * 16, c0 = wn * NI * 16;
  f32x4 acc[MI][NI] = {};

  int nk = (K + 63) >> 6;
  for (int it = 0; it < nk; ++it) {
    int k0 = it * 64;
    // ---- stage A (bf16 copy, no cvt)
    if (BM == 256) {
      int m = tid >> 1, kseg = (tid & 1) * 32;
      const __bf16* ap = A + (size_t)(m0 + m) * ldaK + k0 + kseg;
#pragma unroll
      for (int j = 0; j < 4; ++j)
        *(bf16x8*)&As[m][kseg + j * 8] = *(const bf16x8*)(ap + j * 8);
    } else {
      int m = tid >> 3, kseg = (tid & 7) * 8;
      *(bf16x8*)&As[m][kseg] = *(const bf16x8*)(A + (size_t)(m0 + m) * ldaK + k0 + kseg);
    }
    // ---- stage B (f32 -> bf16, transpose): thread -> (g k-group of 4, n4)
    {
      int g = tid >> 5, n4 = (tid & 31) * 4;
      float4 f[4];
#pragma unroll
      for (int r = 0; r < 4; ++r) {
        int k = k0 + g * 4 + r;
        f[r] = (k < K) ? *(const float4*)&B[(size_t)k * N + n0 + n4]
                       : make_float4(0.f, 0.f, 0.f, 0.f);
      }
#pragma unroll
      for (int i = 0; i < 4; ++i) {
        float c0v = (i == 0) ? f[0].x : (i == 1) ? f[0].y : (i == 2) ? f[0].z : f[0].w;
        float c1v = (i == 0) ? f[1].x : (i == 1) ? f[1].y : (i == 2) ? f[1].z : f[1].w;
        float c2v = (i == 0) ? f[2].x : (i == 1) ? f[2].y : (i == 2) ? f[2].z : f[2].w;
        float c3v = (i == 0) ? f[3].x : (i == 1) ? f[3].y : (i == 2) ? f[3].z : f[3].w;
        bf16x4 o = {(__bf16)c0v, (__bf16)c1v, (__bf16)c2v, (__bf16)c3v};
        *(bf16x4*)&Bs[n4 + i][g * 4] = o;
      }
    }
    __syncthreads();
#pragma unroll
    for (int kk = 0; kk < 64; kk += 32) {
      bf16x8 a[MI], b[NI];
#pragma unroll
      for (int mi = 0; mi < MI; ++mi) a[mi] = *(bf16x8*)&As[r0 + mi * 16 + lrow][kk + lk];
#pragma unroll
      for (int ni = 0; ni < NI; ++ni) b[ni] = *(bf16x8*)&Bs[c0 + ni * 16 + lrow][kk + lk];
#pragma unroll
      for (int mi = 0; mi < MI; ++mi)
#pragma unroll
        for (int ni = 0; ni < NI; ++ni) acc[mi][ni] = MFMA16(a[mi], b[ni], acc[mi][ni]);
    }
    __syncthreads();
  }
#pragma unroll
  for (int mi = 0; mi < MI; ++mi)
#pragma unroll
    for (int ni = 0; ni < NI; ++ni) {
      int colg = n0 + c0 + ni * 16 + lrow;
      float bv = bias[colg];
#pragma unroll
      for (int reg = 0; reg < 4; ++reg) {
        int rowg = m0 + r0 + mi * 16 + (lane >> 4) * 4 + reg;
        C[(size_t)rowg * N + colg] = acc[mi][ni][reg] + bv;
      }
    }
}

// ============ score kernel: per-jtile V.tanh(enc@W1 + b1 + q) partials, BK=64 ============
__global__ __launch_bounds__(512) void k_score_mfma(const float* __restrict__ enc,
                                                    const float* __restrict__ W1,
                                                    const float* __restrict__ b1,
                                                    const float* __restrict__ q,
                                                    const float* __restrict__ V,
                                                    float* __restrict__ score_part) {
  __shared__ __align__(16) __bf16 As[128][72];
  __shared__ __align__(16) __bf16 Bs[128][72];
  int tid = threadIdx.x, lane = tid & 63, w = tid >> 6;
  int wr = w >> 1, wn = w & 1;
  int b = blockIdx.x, m0 = b * 128, n0 = blockIdx.y * 128;
  int lrow = lane & 15, lk = (lane >> 4) * 8;
  int r0 = wr * 32, c0 = wn * 64;
  f32x4 acc[2][4] = {};

  for (int k0 = 0; k0 < ENCD; k0 += 64) {
    // stage A (enc f32 -> bf16): thread -> m=tid>>2, 16 k at (tid&3)*16
    {
      int m = tid >> 2, kseg = (tid & 3) * 16;
      const float* ap = enc + (size_t)(m0 + m) * ENCD + k0 + kseg;
      __bf16 tmp[16];
#pragma unroll
      for (int v = 0; v < 4; ++v) {
        float4 f = *(const float4*)(ap + v * 4);
        tmp[v * 4 + 0] = (__bf16)f.x;
        tmp[v * 4 + 1] = (__bf16)f.y;
        tmp[v * 4 + 2] = (__bf16)f.z;
        tmp[v * 4 + 3] = (__bf16)f.w;
      }
      *(bf16x8*)&As[m][kseg] = *(bf16x8*)&tmp[0];
      *(bf16x8*)&As[m][kseg + 8] = *(bf16x8*)&tmp[8];
    }
    // stage B (W1 f32 -> bf16 transpose)
    {
      int g = tid >> 5, n4 = (tid & 31) * 4;
      float4 f[4];
#pragma unroll
      for (int r = 0; r < 4; ++r)
        f[r] = *(const float4*)&W1[(size_t)(k0 + g * 4 + r) * DECU + n0 + n4];
#pragma unroll
      for (int i = 0; i < 4; ++i) {
        float c0v = (i == 0) ? f[0].x : (i == 1) ? f[0].y : (i == 2) ? f[0].z : f[0].w;
        float c1v = (i == 0) ? f[1].x : (i == 1) ? f[1].y : (i == 2) ? f[1].z : f[1].w;
        float c2v = (i == 0) ? f[2].x : (i == 1) ? f[2].y : (i == 2) ? f[2].z : f[2].w;
        float c3v = (i == 0) ? f[3].x : (i == 1) ? f[3].y : (i == 2) ? f[3].z : f[3].w;
        bf16x4 o = {(__bf16)c0v, (__bf16)c1v, (__bf16)c2v, (__bf16)c3v};
        *(bf16x4*)&Bs[n4 + i][g * 4] = o;
      }
    }
    __syncthreads();
#pragma unroll
    for (int kk = 0; kk < 64; kk += 32) {
      bf16x8 a0 = *(bf16x8*)&As[r0 + lrow][kk + lk];
      bf16x8 a1 = *(bf16x8*)&As[r0 + 16 + lrow][kk + lk];
#pragma unroll
      for (int ni = 0; ni < 4; ++ni) {
        bf16x8 bb = *(bf16x8*)&Bs[c0 + ni * 16 + lrow][kk + lk];
        acc[0][ni] = MFMA16(a0, bb, acc[0][ni]);
        acc[1][ni] = MFMA16(a1, bb, acc[1][ni]);
      }
    }
    __syncthreads();
  }
  // epilogue: tanh + dot V, 16-lane reduce
  float psum[2][4] = {};
#pragma unroll
  for (int mi = 0; mi < 2; ++mi)
#pragma unroll
    for (int ni = 0; ni < 4; ++ni) {
      int j = n0 + c0 + ni * 16 + lrow;
      float vj = V[j], b1j = b1[j], qv = q[b * DECU + j];
#pragma unroll
      for (int reg = 0; reg < 4; ++reg)
        psum[mi][reg] += vj * tanhf(acc[mi][ni][reg] + b1j + qv);
    }
#pragma unroll
  for (int off = 1; off < 16; off <<= 1)
#pragma unroll
    for (int mi = 0; mi < 2; ++mi)
#pragma unroll
      for (int reg = 0; reg < 4; ++reg)
        psum[mi][reg] += __shfl_xor(psum[mi][reg], off);
  if (lrow == 0) {
#pragma unroll
    for (int mi = 0; mi < 2; ++mi)
#pragma unroll
      for (int reg = 0; reg < 4; ++reg) {
        int rowg = m0 + r0 + mi * 16 + (lane >> 4) * 4 + reg;
        score_part[(size_t)rowg * 8 + blockIdx.y * 2 + wn] = psum[mi][reg];
      }
  }
}

// ---------------- softmax over S + context(+emb) -> xi_bf ----------------
// grid (256, 2): blockIdx.y = k-half for context.
__global__ __launch_bounds__(256) void k_attn_ctx(const float* __restrict__ score_part,
                                                  const float* __restrict__ bV,
                                                  const float* __restrict__ enc,
                                                  const int* __restrict__ x,
                                                  const float* __restrict__ emb,
                                                  float* __restrict__ attn_out,
                                                  __bf16* __restrict__ xi_bf) {
  int b = blockIdx.x, half = blockIdx.y, t = threadIdx.x;
  __shared__ float a_s[S_];
  if (t < S_) {
    float s = bV[0];
#pragma unroll
    for (int jt = 0; jt < 8; ++jt) s += score_part[(size_t)(b * S_ + t) * 8 + jt];
    a_s[t] = s;
  }
  __syncthreads();
  float mx = -INFINITY;
  for (int s = 0; s < S_; ++s) mx = fmaxf(mx, a_s[s]);
  float sum = 0.f;
  for (int s = 0; s < S_; ++s) sum += __expf(a_s[s] - mx);
  float inv = 1.f / sum;
  __syncthreads();
  if (t < S_) a_s[t] = __expf(a_s[t] - mx) * inv;
  __syncthreads();
  if (half == 0) {
    if (t < S_) attn_out[b * S_ + t] = a_s[t];
    // embedding + pad
    int xb = x[b];
    if (t < 75) {
      float4 f = *(const float4*)&emb[(size_t)xb * EMB_ + t * 4];
      bf16x4 o = {(__bf16)f.x, (__bf16)f.y, (__bf16)f.z, (__bf16)f.w};
      *(bf16x4*)&xi_bf[(size_t)b * KPADX + ENCD + t * 4] = o;
    } else if (t < 80) {
      bf16x4 z = {(__bf16)0.f, (__bf16)0.f, (__bf16)0.f, (__bf16)0.f};
      *(bf16x4*)&xi_bf[(size_t)b * KPADX + INDIM + (t - 75) * 4] = z;
    }
  }
  // context: this block's 512 k-cols
  int c = half * 512 + t * 2;
  float ax = 0.f, ay = 0.f;
  const float* ebase = enc + (size_t)b * S_ * ENCD + c;
#pragma unroll 4
  for (int s = 0; s < S_; ++s) {
    float2 e = *(const float2*)(ebase + (size_t)s * ENCD);
    float av = a_s[s];
    ax += av * e.x;
    ay += av * e.y;
  }
  bf16x2 o = {(__bf16)ax, (__bf16)ay};
  *(bf16x2*)&xi_bf[(size_t)b * KPADX + c] = o;
}

// ---------------- GRU gates (+ h in bf16) ----------------
__global__ __launch_bounds__(256) void k_gates(const float* __restrict__ mx,
                                               const float* __restrict__ mh,
                                               const float* __restrict__ state,
                                               float* __restrict__ h_out,
                                               __bf16* __restrict__ h_bf) {
  int idx = blockIdx.x * 256 + threadIdx.x;
  int b = idx >> 10, j = idx & 1023;
  const float* mxr = mx + (size_t)b * G3;
  const float* mhr = mh + (size_t)b * G3;
  float z = 1.f / (1.f + __expf(-(mxr[j] + mhr[j])));
  float r = 1.f / (1.f + __expf(-(mxr[UNITS + j] + mhr[UNITS + j])));
  float hh = tanhf(mxr[2 * UNITS + j] + r * mhr[2 * UNITS + j]);
  float st = state[idx];
  float h = z * st + (1.f - z) * hh;
  h_out[idx] = h;
  h_bf[idx] = (__bf16)h;
}

// ---------------- register-resident vocab softmax: 1 read + 1 write ----------------
__global__ __launch_bounds__(1024) void k_softmax(float* __restrict__ logits) {
  int b = blockIdx.x, t = threadIdx.x;
  int lane = t & 63, w = t >> 6;
  float4* row4 = (float4*)(logits + (size_t)b * VOCAB);  // 8000 float4
  __shared__ float redm[16];
  __shared__ float reds[16];
  float4 v[8];
  float m = -INFINITY;
#pragma unroll
  for (int i = 0; i < 8; ++i) {
    int i4 = i * 1024 + t;
    if (i4 < 8000) {
      v[i] = row4[i4];
      m = fmaxf(m, fmaxf(fmaxf(v[i].x, v[i].y), fmaxf(v[i].z, v[i].w)));
    } else {
      v[i] = make_float4(-INFINITY, -INFINITY, -INFINITY, -INFINITY);
    }
  }
#pragma unroll
  for (int o = 32; o >= 1; o >>= 1) m = fmaxf(m, __shfl_xor(m, o));
  if (lane == 0) redm[w] = m;
  __syncthreads();
  float m2 = -INFINITY;
#pragma unroll
  for (int i = 0; i < 16; ++i) m2 = fmaxf(m2, redm[i]);
  float s = 0.f;
#pragma unroll
  for (int i = 0; i < 8; ++i) {
    v[i].x = __expf(v[i].x - m2);
    v[i].y = __expf(v[i].y - m2);
    v[i].z = __expf(v[i].z - m2);
    v[i].w = __expf(v[i].w - m2);
    s += v[i].x + v[i].y + v[i].z + v[i].w;
  }
#pragma unroll
  for (int o = 32; o >= 1; o >>= 1) s += __shfl_xor(s, o);
  if (lane == 0) reds[w] = s;
  __syncthreads();
  float s2 = 0.f;
#pragma unroll
  for (int i = 0; i < 16; ++i) s2 += reds[i];
  float inv = 1.f / s2;
#pragma unroll
  for (int i = 0; i < 8; ++i) {
    int i4 = i * 1024 + t;
    if (i4 < 8000) {
      float4 o = make_float4(v[i].x * inv, v[i].y * inv, v[i].z * inv, v[i].w * inv);
      row4[i4] = o;
    }
  }
}

extern "C" void kernel_launch(void* const* d_in, const int* in_sizes, int n_in,
                              void* d_out, int out_size, void* d_ws, size_t ws_size,
                              hipStream_t stream) {
  const int*   x     = (const int*)d_in[0];
  const float* state = (const float*)d_in[1];
  const float* enc   = (const float*)d_in[2];
  const float* emb   = (const float*)d_in[3];
  const float* W1    = (const float*)d_in[4];
  const float* b1    = (const float*)d_in[5];
  const float* W2    = (const float*)d_in[6];
  const float* b2    = (const float*)d_in[7];
  const float* V     = (const float*)d_in[8];
  const float* bV    = (const float*)d_in[9];
  const float* gru_k = (const float*)d_in[10];
  const float* gru_rk= (const float*)d_in[11];
  const float* gru_b = (const float*)d_in[12];
  const float* fc_W  = (const float*)d_in[13];
  const float* fc_b  = (const float*)d_in[14];

  float* out   = (float*)d_out;
  float* probs = out;                               // 256*32000
  float* h_out = out + (size_t)B_ * VOCAB;          // 256*1024
  float* attn  = h_out + (size_t)B_ * UNITS;        // 256*128

  float* ws      = (float*)d_ws;
  float* q       = ws;                              // 131072 f32
  float* sc_part = q + B_ * DECU;                   // 262144 f32
  float* mx      = sc_part + (size_t)B_ * S_ * 8;   // 786432 f32
  float* mh      = mx + (size_t)B_ * G3;            // 786432 f32
  __bf16* state_bf = (__bf16*)(mh + (size_t)B_ * G3);          // 262144 bf16
  __bf16* xi_bf    = state_bf + (size_t)B_ * UNITS;            // 256*1344 bf16
  __bf16* h_bf     = (__bf16*)sc_part;  // alias: sc_part dead after k_attn_ctx

  k_cvt_state<<<256, 256, 0, stream>>>(state, state_bf);
  // q = state @ W2 + b2
  k_gemm<64><<<dim3(4, 4), 512, 0, stream>>>(state_bf, UNITS, W2, b2, q, UNITS, DECU);
  // score partials
  k_score_mfma<<<dim3(B_, 4), 512, 0, stream>>>(enc, W1, b1, q, V, sc_part);
  // softmax over S + context + emb -> xi_bf
  k_attn_ctx<<<dim3(B_, 2), 256, 0, stream>>>(sc_part, bV, enc, x, emb, attn, xi_bf);
  // GRU GEMMs
  k_gemm<64><<<dim3(4, 24), 512, 0, stream>>>(xi_bf, KPADX, gru_k, gru_b, mx, INDIM, G3);
  k_gemm<64><<<dim3(4, 24), 512, 0, stream>>>(state_bf, UNITS, gru_rk, gru_b + G3, mh, UNITS, G3);
  // gates -> h (f32 out + bf16 ws)
  k_gates<<<(B_ * UNITS) / 256, 256, 0, stream>>>(mx, mh, state, h_out, h_bf);
  // FC logits
  k_gemm<256><<<dim3(1, VOCAB / 128), 512, 0, stream>>>(h_bf, UNITS, fc_W, fc_b, probs, UNITS, VOCAB);
  // vocab softmax
  k_softmax<<<B_, 1024, 0, stream>>>(probs);
}

// Round 5
// 205.324 us; speedup vs baseline: 7.0380x; 1.7704x over previous
//
#include <hip/hip_runtime.h>
#include <math.h>

#define B_    256
#define S_    128
#define ENCD  1024
#define DECU  512
#define UNITS 1024
#define VOCAB 32000
#define EMB_  300
#define INDIM 1324   // ENCD + EMB
#define KPADX 1344   // INDIM padded to 64
#define G3    3072   // 3*UNITS

typedef __bf16 bf16x8 __attribute__((ext_vector_type(8)));
typedef __bf16 bf16x4 __attribute__((ext_vector_type(4)));
typedef __bf16 bf16x2 __attribute__((ext_vector_type(2)));
typedef float  f32x4  __attribute__((ext_vector_type(4)));

#define MFMA16(a, b, c) __builtin_amdgcn_mfma_f32_16x16x32_bf16((a), (b), (c), 0, 0, 0)

// LDS tile: row stride 64 bf16 (128 B), XOR-swizzled 16B slots (T2): bank-conflict-free b128.
__device__ __forceinline__ int swz(int row, int e) { return row * 64 + (e ^ ((row & 7) << 3)); }

__device__ __forceinline__ float fast_tanh(float x) {
  x = fminf(fmaxf(x, -15.f), 15.f);
  float e = __expf(2.f * x);
  return (e - 1.f) / (e + 1.f);
}

// ---------------- convert state f32 -> bf16 ----------------
__global__ __launch_bounds__(256) void k_cvt_state(const float* __restrict__ in,
                                                   __bf16* __restrict__ out) {
  int i4 = blockIdx.x * 256 + threadIdx.x;   // 65536 float4s
  float4 f = *(const float4*)(in + (size_t)i4 * 4);
  bf16x4 o = {(__bf16)f.x, (__bf16)f.y, (__bf16)f.z, (__bf16)f.w};
  *(bf16x4*)(out + (size_t)i4 * 4) = o;
}

// ---------------- transpose+convert W1 [1024][512] f32 -> W1t [512][1024] bf16 ----------------
__global__ __launch_bounds__(1024) void k_w1t(const float* __restrict__ W1,
                                              __bf16* __restrict__ W1t) {
  int n = blockIdx.x;      // 512
  int k = threadIdx.x;     // 1024
  W1t[(size_t)n * 1024 + k] = (__bf16)W1[(size_t)k * 512 + n];
}

// ============ generic MFMA GEMM: C[M][N] = A_bf[M][ldaK] @ B_f32[K][N] + bias ============
// BN=64, BK=64, 512 threads (8 waves), swizzled LDS, reg-prefetch pipeline.
template <int BM>
__global__ __launch_bounds__(512) void k_gemm(const __bf16* __restrict__ A, int ldaK,
                                              const float* __restrict__ B,
                                              const float* __restrict__ bias,
                                              float* __restrict__ C, int K, int N) {
  constexpr int WR = (BM == 256) ? 4 : 2;
  constexpr int WN = 8 / WR;
  constexpr int MI = BM / (WR * 16);
  constexpr int NI = 64 / (WN * 16);
  __shared__ __align__(16) __bf16 As[BM * 64];
  __shared__ __align__(16) __bf16 Bs[64 * 64];
  int tid = threadIdx.x, lane = tid & 63, w = tid >> 6;
  int wr = (BM == 256) ? (w >> 1) : (w >> 2);
  int wn = (BM == 256) ? (w & 1) : (w & 3);
  int m0 = blockIdx.x * BM, n0 = blockIdx.y * 64;
  int lrow = lane & 15, lk = (lane >> 4) * 8;
  int r0 = wr * MI * 16, c0 = wn * NI * 16;
  f32x4 acc[MI][NI] = {};

  constexpr int ACH = (BM == 256) ? 4 : 1;
  bf16x8 pfa[ACH];
  float pfb[8];
  int am = (BM == 256) ? (tid >> 1) : (tid >> 3);
  int aks = (BM == 256) ? ((tid & 1) * 32) : ((tid & 7) * 8);
  const __bf16* arow = A + (size_t)(m0 + am) * ldaK + aks;
  int bn = tid & 63, bks = (tid >> 6) * 8;

  int nk = (K + 63) >> 6;
#pragma unroll
  for (int c = 0; c < ACH; ++c) pfa[c] = *(const bf16x8*)(arow + c * 8);
#pragma unroll
  for (int i = 0; i < 8; ++i) { int k = bks + i; pfb[i] = (k < K) ? B[(size_t)k * N + n0 + bn] : 0.f; }

  for (int it = 0; it < nk; ++it) {
#pragma unroll
    for (int c = 0; c < ACH; ++c) *(bf16x8*)&As[swz(am, aks + c * 8)] = pfa[c];
    {
      __bf16 tb[8];
#pragma unroll
      for (int i = 0; i < 8; ++i) tb[i] = (__bf16)pfb[i];
      *(bf16x8*)&Bs[swz(bn, bks)] = *(bf16x8*)&tb[0];
    }
    __syncthreads();
    if (it + 1 < nk) {
      int k0 = (it + 1) * 64;
#pragma unroll
      for (int c = 0; c < ACH; ++c) pfa[c] = *(const bf16x8*)(arow + k0 + c * 8);
#pragma unroll
      for (int i = 0; i < 8; ++i) { int k = k0 + bks + i; pfb[i] = (k < K) ? B[(size_t)k * N + n0 + bn] : 0.f; }
    }
#pragma unroll
    for (int kk = 0; kk < 64; kk += 32) {
      bf16x8 av[MI], bv[NI];
#pragma unroll
      for (int mi = 0; mi < MI; ++mi) { int r = r0 + mi * 16 + lrow; av[mi] = *(bf16x8*)&As[swz(r, kk + lk)]; }
#pragma unroll
      for (int ni = 0; ni < NI; ++ni) { int r = c0 + ni * 16 + lrow; bv[ni] = *(bf16x8*)&Bs[swz(r, kk + lk)]; }
#pragma unroll
      for (int mi = 0; mi < MI; ++mi)
#pragma unroll
        for (int ni = 0; ni < NI; ++ni) acc[mi][ni] = MFMA16(av[mi], bv[ni], acc[mi][ni]);
    }
    __syncthreads();
  }
#pragma unroll
  for (int mi = 0; mi < MI; ++mi)
#pragma unroll
    for (int ni = 0; ni < NI; ++ni) {
      int colg = n0 + c0 + ni * 16 + lrow;
      float bvv = bias[colg];
#pragma unroll
      for (int reg = 0; reg < 4; ++reg) {
        int rowg = m0 + r0 + mi * 16 + (lane >> 4) * 4 + reg;
        C[(size_t)rowg * N + colg] = acc[mi][ni][reg] + bvv;
      }
    }
}

// ============ fused attention: score GEMM + softmax + context + xi, one block per b ============
// 512 threads. acc covers all 512 j (BM=128 rows, BN=512). enc staged once per k-tile.
__global__ __launch_bounds__(512) void k_attn_fused(const float* __restrict__ enc,
                                                    const __bf16* __restrict__ W1t,
                                                    const float* __restrict__ b1,
                                                    const float* __restrict__ q,
                                                    const float* __restrict__ V,
                                                    const float* __restrict__ bV,
                                                    const int* __restrict__ x,
                                                    const float* __restrict__ emb,
                                                    float* __restrict__ attn_out,
                                                    __bf16* __restrict__ xi_bf) {
  __shared__ __align__(16) __bf16 As[128 * 64];   // enc k-tile
  __shared__ __align__(16) __bf16 Bs[512 * 64];   // W1t k-tile (all 512 j)
  __shared__ float sc_p[4][128];
  __shared__ float sc_s[128];
  __shared__ float aw_s[128];
  int b = blockIdx.x;
  int tid = threadIdx.x, lane = tid & 63, w = tid >> 6;
  int wr = w >> 2, wn = w & 3;          // 2 row-halves x 4 col-quarters
  int lrow = lane & 15, lk = (lane >> 4) * 8;
  f32x4 acc[4][8] = {};

  // prefetch registers
  float4 pfa[4];
  bf16x8 pfb[8];
  int am = tid >> 2, aks = (tid & 3) * 16;
  const float* arow = enc + ((size_t)b * 128 + am) * ENCD + aks;
  // B staging: thread covers rows bn+64j (j=0..7), k-slot bks (8 lanes span 128B of a row)
  int bn = tid >> 3, bks = (tid & 7) * 8;
  {
    pfa[0] = *(const float4*)arow; pfa[1] = *(const float4*)(arow + 4);
    pfa[2] = *(const float4*)(arow + 8); pfa[3] = *(const float4*)(arow + 12);
#pragma unroll
    for (int j = 0; j < 8; ++j)
      pfb[j] = *(const bf16x8*)(W1t + (size_t)(bn + 64 * j) * 1024 + bks);
  }
  for (int it = 0; it < 16; ++it) {
    // stage current tile
    __bf16 tmp[16];
#pragma unroll
    for (int v = 0; v < 4; ++v) {
      tmp[v * 4 + 0] = (__bf16)pfa[v].x; tmp[v * 4 + 1] = (__bf16)pfa[v].y;
      tmp[v * 4 + 2] = (__bf16)pfa[v].z; tmp[v * 4 + 3] = (__bf16)pfa[v].w;
    }
    *(bf16x8*)&As[swz(am, aks)]     = *(bf16x8*)&tmp[0];
    *(bf16x8*)&As[swz(am, aks + 8)] = *(bf16x8*)&tmp[8];
#pragma unroll
    for (int j = 0; j < 8; ++j) *(bf16x8*)&Bs[swz(bn + 64 * j, bks)] = pfb[j];
    __syncthreads();
    // prefetch next tile (hidden under MFMA)
    if (it + 1 < 16) {
      int k0 = (it + 1) * 64;
      const float* p = arow + k0;
      pfa[0] = *(const float4*)p; pfa[1] = *(const float4*)(p + 4);
      pfa[2] = *(const float4*)(p + 8); pfa[3] = *(const float4*)(p + 12);
#pragma unroll
      for (int j = 0; j < 8; ++j)
        pfb[j] = *(const bf16x8*)(W1t + (size_t)(bn + 64 * j) * 1024 + k0 + bks);
    }
#pragma unroll
    for (int kk = 0; kk < 64; kk += 32) {
      bf16x8 av[4], bv[8];
#pragma unroll
      for (int mi = 0; mi < 4; ++mi) { int r = wr * 64 + mi * 16 + lrow; av[mi] = *(bf16x8*)&As[swz(r, kk + lk)]; }
#pragma unroll
      for (int ni = 0; ni < 8; ++ni) { int r = wn * 128 + ni * 16 + lrow; bv[ni] = *(bf16x8*)&Bs[swz(r, kk + lk)]; }
#pragma unroll
      for (int mi = 0; mi < 4; ++mi)
#pragma unroll
        for (int ni = 0; ni < 8; ++ni) acc[mi][ni] = MFMA16(av[mi], bv[ni], acc[mi][ni]);
    }
    __syncthreads();
  }
  // ---- epilogue: tanh + dot V, reduce over 16-lane groups, cross-wave via LDS
  float psum[4][4] = {};
#pragma unroll
  for (int mi = 0; mi < 4; ++mi)
#pragma unroll
    for (int ni = 0; ni < 8; ++ni) {
      int j = wn * 128 + ni * 16 + lrow;
      float vj = V[j], b1j = b1[j], qv = q[(size_t)b * DECU + j];
#pragma unroll
      for (int reg = 0; reg < 4; ++reg)
        psum[mi][reg] += vj * fast_tanh(acc[mi][ni][reg] + b1j + qv);
    }
#pragma unroll
  for (int off = 1; off < 16; off <<= 1)
#pragma unroll
    for (int mi = 0; mi < 4; ++mi)
#pragma unroll
      for (int reg = 0; reg < 4; ++reg)
        psum[mi][reg] += __shfl_xor(psum[mi][reg], off);
  if (lrow == 0) {
#pragma unroll
    for (int mi = 0; mi < 4; ++mi)
#pragma unroll
      for (int reg = 0; reg < 4; ++reg) {
        int rl = wr * 64 + mi * 16 + (lane >> 4) * 4 + reg;
        sc_p[wn][rl] = psum[mi][reg];
      }
  }
  __syncthreads();
  // ---- softmax over S=128
  if (tid < S_) sc_s[tid] = bV[0] + sc_p[0][tid] + sc_p[1][tid] + sc_p[2][tid] + sc_p[3][tid];
  __syncthreads();
  float mx = -INFINITY;
  for (int s = 0; s < S_; ++s) mx = fmaxf(mx, sc_s[s]);
  float sum = 0.f;
  for (int s = 0; s < S_; ++s) sum += __expf(sc_s[s] - mx);
  float inv = 1.f / sum;
  if (tid < S_) {
    float av = __expf(sc_s[tid] - mx) * inv;
    aw_s[tid] = av;
    attn_out[(size_t)b * S_ + tid] = av;
  }
  __syncthreads();
  // ---- context (enc re-read from L2/L3) -> xi_bf[0:1024]
  int c = tid * 2;
  float ax = 0.f, ay = 0.f;
  const float* eb = enc + (size_t)b * S_ * ENCD + c;
#pragma unroll 8
  for (int s = 0; s < S_; ++s) {
    float2 e = *(const float2*)(eb + (size_t)s * ENCD);
    float av = aw_s[s];
    ax = fmaf(av, e.x, ax);
    ay = fmaf(av, e.y, ay);
  }
  bf16x2 o = {(__bf16)ax, (__bf16)ay};
  *(bf16x2*)&xi_bf[(size_t)b * KPADX + c] = o;
  // ---- embedding + pad -> xi_bf[1024:1344]
  int xb = x[b];
  if (tid < 75) {
    float4 f = *(const float4*)&emb[(size_t)xb * EMB_ + tid * 4];
    bf16x4 o4 = {(__bf16)f.x, (__bf16)f.y, (__bf16)f.z, (__bf16)f.w};
    *(bf16x4*)&xi_bf[(size_t)b * KPADX + ENCD + tid * 4] = o4;
  } else if (tid < 80) {
    bf16x4 z = {(__bf16)0.f, (__bf16)0.f, (__bf16)0.f, (__bf16)0.f};
    *(bf16x4*)&xi_bf[(size_t)b * KPADX + INDIM + (tid - 75) * 4] = z;
  }
}

// ---------------- GRU gates (+ h in bf16) ----------------
__global__ __launch_bounds__(256) void k_gates(const float* __restrict__ mx,
                                               const float* __restrict__ mh,
                                               const float* __restrict__ state,
                                               float* __restrict__ h_out,
                                               __bf16* __restrict__ h_bf) {
  int idx = blockIdx.x * 256 + threadIdx.x;
  int b = idx >> 10, j = idx & 1023;
  const float* mxr = mx + (size_t)b * G3;
  const float* mhr = mh + (size_t)b * G3;
  float z = 1.f / (1.f + __expf(-(mxr[j] + mhr[j])));
  float r = 1.f / (1.f + __expf(-(mxr[UNITS + j] + mhr[UNITS + j])));
  float hh = tanhf(mxr[2 * UNITS + j] + r * mhr[2 * UNITS + j]);
  float st = state[idx];
  float h = z * st + (1.f - z) * hh;
  h_out[idx] = h;
  h_bf[idx] = (__bf16)h;
}

// ---------------- register-resident vocab softmax ----------------
__global__ __launch_bounds__(1024) void k_softmax(float* __restrict__ logits) {
  int b = blockIdx.x, t = threadIdx.x;
  int lane = t & 63, w = t >> 6;
  float4* row4 = (float4*)(logits + (size_t)b * VOCAB);  // 8000 float4
  __shared__ float redm[16];
  __shared__ float reds[16];
  float4 v[8];
  float m = -INFINITY;
#pragma unroll
  for (int i = 0; i < 8; ++i) {
    int i4 = i * 1024 + t;
    if (i4 < 8000) {
      v[i] = row4[i4];
      m = fmaxf(m, fmaxf(fmaxf(v[i].x, v[i].y), fmaxf(v[i].z, v[i].w)));
    } else {
      v[i] = make_float4(-INFINITY, -INFINITY, -INFINITY, -INFINITY);
    }
  }
#pragma unroll
  for (int o = 32; o >= 1; o >>= 1) m = fmaxf(m, __shfl_xor(m, o));
  if (lane == 0) redm[w] = m;
  __syncthreads();
  float m2 = -INFINITY;
#pragma unroll
  for (int i = 0; i < 16; ++i) m2 = fmaxf(m2, redm[i]);
  float s = 0.f;
#pragma unroll
  for (int i = 0; i < 8; ++i) {
    v[i].x = __expf(v[i].x - m2);
    v[i].y = __expf(v[i].y - m2);
    v[i].z = __expf(v[i].z - m2);
    v[i].w = __expf(v[i].w - m2);
    s += v[i].x + v[i].y + v[i].z + v[i].w;
  }
#pragma unroll
  for (int o = 32; o >= 1; o >>= 1) s += __shfl_xor(s, o);
  if (lane == 0) reds[w] = s;
  __syncthreads();
  float s2 = 0.f;
#pragma unroll
  for (int i = 0; i < 16; ++i) s2 += reds[i];
  float inv = 1.f / s2;
#pragma unroll
  for (int i = 0; i < 8; ++i) {
    int i4 = i * 1024 + t;
    if (i4 < 8000)
      row4[i4] = make_float4(v[i].x * inv, v[i].y * inv, v[i].z * inv, v[i].w * inv);
  }
}

extern "C" void kernel_launch(void* const* d_in, const int* in_sizes, int n_in,
                              void* d_out, int out_size, void* d_ws, size_t ws_size,
                              hipStream_t stream) {
  const int*   x     = (const int*)d_in[0];
  const float* state = (const float*)d_in[1];
  const float* enc   = (const float*)d_in[2];
  const float* emb   = (const float*)d_in[3];
  const float* W1    = (const float*)d_in[4];
  const float* b1    = (const float*)d_in[5];
  const float* W2    = (const float*)d_in[6];
  const float* b2    = (const float*)d_in[7];
  const float* V     = (const float*)d_in[8];
  const float* bV    = (const float*)d_in[9];
  const float* gru_k = (const float*)d_in[10];
  const float* gru_rk= (const float*)d_in[11];
  const float* gru_b = (const float*)d_in[12];
  const float* fc_W  = (const float*)d_in[13];
  const float* fc_b  = (const float*)d_in[14];

  float* out   = (float*)d_out;
  float* probs = out;                               // 256*32000
  float* h_out = out + (size_t)B_ * VOCAB;          // 256*1024
  float* attn  = h_out + (size_t)B_ * UNITS;        // 256*128

  float* ws = (float*)d_ws;
  float* q  = ws;                                   // 131072 f32
  float* mx = q + (size_t)B_ * DECU;                // 786432 f32
  float* mh = mx + (size_t)B_ * G3;                 // 786432 f32
  __bf16* state_bf = (__bf16*)(mh + (size_t)B_ * G3);   // 262144 bf16
  __bf16* xi_bf    = state_bf + (size_t)B_ * UNITS;     // 256*1344 bf16
  __bf16* h_bf     = xi_bf + (size_t)B_ * KPADX;        // 262144 bf16
  __bf16* W1t      = h_bf + (size_t)B_ * UNITS;         // 512*1024 bf16

  k_cvt_state<<<256, 256, 0, stream>>>(state, state_bf);
  k_w1t<<<512, 1024, 0, stream>>>(W1, W1t);
  // q = state @ W2 + b2
  k_gemm<64><<<dim3(4, 8), 512, 0, stream>>>(state_bf, UNITS, W2, b2, q, UNITS, DECU);
  // fused attention: score + softmax + context + xi
  k_attn_fused<<<B_, 512, 0, stream>>>(enc, W1t, b1, q, V, bV, x, emb, attn, xi_bf);
  // GRU GEMMs
  k_gemm<64><<<dim3(4, 48), 512, 0, stream>>>(xi_bf, KPADX, gru_k, gru_b, mx, INDIM, G3);
  k_gemm<64><<<dim3(4, 48), 512, 0, stream>>>(state_bf, UNITS, gru_rk, gru_b + G3, mh, UNITS, G3);
  // gates -> h
  k_gates<<<(B_ * UNITS) / 256, 256, 0, stream>>>(mx, mh, state, h_out, h_bf);
  // FC logits
  k_gemm<256><<<dim3(1, VOCAB / 64), 512, 0, stream>>>(h_bf, UNITS, fc_W, fc_b, probs, UNITS, VOCAB);
  // vocab softmax
  k_softmax<<<B_, 1024, 0, stream>>>(probs);
}